// Round 14
// baseline (14396.909 us; speedup 1.0000x reference)
//
#include <hip/hip_runtime.h>
#include <hip/hip_bf16.h>
#include <math.h>

#define Bb 64
#define Tt 512
#define Dd 1024
#define Uu 1024
#define NWG 64       // persistent WGs
#define NTHR 512     // 8 waves: 0-3 zx(t+1) K=256 each, 4-7 zh(t) K=256 each
#define UPW 16       // u's per WG
#define NCOL 64      // packed cols per WG = 4 gates * 16 u
#define KTOT 2048    // D + U packed K
#define ZP 68        // LDS partial row stride (floats)
#define GUARD (1 << 22)

#define BUFF (Bb * ZP)              // floats per partial buffer
#define DYN_LDS (6 * BUFF * 4)      // zxA0,zxB0 | zxA1,zxB1 | zhA,zhB = 104448 B

typedef __attribute__((ext_vector_type(8))) short bf16x8;
typedef __attribute__((ext_vector_type(4))) float f32x4;
typedef __attribute__((ext_vector_type(2))) float f32x2;

// ---- one-time prep ---------------------------------------------------------

__global__ void cast_x_bf16(const float* __restrict__ in, __hip_bfloat16* __restrict__ out, int n4) {
  int i = blockIdx.x * blockDim.x + threadIdx.x;
  int stride = gridDim.x * blockDim.x;
  for (; i < n4; i += stride) {
    float4 v = reinterpret_cast<const float4*>(in)[i];
    __hip_bfloat16* o = out + 4 * (size_t)i;
    o[0] = __float2bfloat16(v.x);
    o[1] = __float2bfloat16(v.y);
    o[2] = __float2bfloat16(v.z);
    o[3] = __float2bfloat16(v.w);
  }
}

// fp32 [K][4096] -> pWT[(c*64 + pc)*2048 + koff + k] bf16,
// col = g*1024 + c*16 + uu -> c=(col&1023)>>4, pc = g*16 + uu.
__global__ void pack_w(const float* __restrict__ in, __hip_bfloat16* __restrict__ pWT, int koff) {
  __shared__ float tile[32][33];
  int n0 = blockIdx.x * 32, k0 = blockIdx.y * 32;
  int tx = threadIdx.x, ty = threadIdx.y;
#pragma unroll
  for (int p = 0; p < 4; ++p) {
    int r = ty + p * 8;
    tile[r][tx] = in[(size_t)(k0 + r) * (4 * Uu) + n0 + tx];
  }
  __syncthreads();
#pragma unroll
  for (int p = 0; p < 4; ++p) {
    int r = ty + p * 8;
    int col = n0 + r;
    int c = (col & (Uu - 1)) >> 4;
    int pc = (col >> 10) * 16 + (col & 15);
    pWT[((size_t)(c * NCOL + pc)) * KTOT + koff + k0 + tx] = __float2bfloat16(tile[tx][r]);
  }
}

// ---- helpers ---------------------------------------------------------------

__device__ __forceinline__ unsigned pollSys(const unsigned* p) {
  return __hip_atomic_load(p, __ATOMIC_RELAXED, __HIP_MEMORY_SCOPE_SYSTEM);
}
__device__ __forceinline__ void storeSys(unsigned* p, unsigned v) {
  __hip_atomic_store(p, v, __ATOMIC_RELAXED, __HIP_MEMORY_SCOPE_SYSTEM);
}
__device__ __forceinline__ float sigm(float v) { return 1.f / (1.f + __expf(-v)); }

#define WAITV(n)                                             \
  do {                                                       \
    asm volatile("s_waitcnt vmcnt(" #n ")" ::: "memory");    \
    __builtin_amdgcn_sched_barrier(0);                       \
  } while (0)

// zx batch (kk): 4 A (bf16 16B, plain) + 4 B (bf16 16B, plain) = 8 loads
#define XI(S, kk)                                                              \
  {                                                                            \
    _Pragma("unroll") for (int mt = 0; mt < 4; ++mt) {                         \
      asm volatile("global_load_dwordx4 %0, %1, off offset:%2"                 \
                   : "=&v"(S[mt]) : "v"(xaddr[mt]), "i"((kk) * 64)             \
                   : "memory");                                                \
    }                                                                          \
    _Pragma("unroll") for (int ct = 0; ct < 4; ++ct) {                         \
      asm volatile("global_load_dwordx4 %0, %1, off offset:%2"                 \
                   : "=&v"(S[4 + ct]) : "v"(baddr[ct]), "i"((kk) * 64)         \
                   : "memory");                                                \
    }                                                                          \
  }

// zh batch (kk): 4 A (bf16 16B, sc0 sc1 MALL-coherent) + 4 B (plain)
#define HI(S, kk)                                                              \
  {                                                                            \
    _Pragma("unroll") for (int mt = 0; mt < 4; ++mt) {                         \
      asm volatile("global_load_dwordx4 %0, %1, off offset:%2 sc0 sc1"         \
                   : "=&v"(S[mt]) : "v"(haddr[mt]), "i"((kk) * 64)             \
                   : "memory");                                                \
    }                                                                          \
    _Pragma("unroll") for (int ct = 0; ct < 4; ++ct) {                         \
      asm volatile("global_load_dwordx4 %0, %1, off offset:%2"                 \
                   : "=&v"(S[4 + ct]) : "v"(baddr[ct]), "i"((kk) * 64)         \
                   : "memory");                                                \
    }                                                                          \
  }

#define CNS(S)                                                                 \
  {                                                                            \
    _Pragma("unroll") for (int mt = 0; mt < 4; ++mt) {                         \
      bf16x8 af = __builtin_bit_cast(bf16x8, S[mt]);                           \
      _Pragma("unroll") for (int ct = 0; ct < 4; ++ct)                         \
        acc[mt][ct] = __builtin_amdgcn_mfma_f32_16x16x32_bf16(                 \
            af, __builtin_bit_cast(bf16x8, S[4 + ct]), acc[mt][ct], 0, 0, 0);  \
    }                                                                          \
  }

#define LADDER(ISSUE)                                                          \
  ISSUE(s0, 0); ISSUE(s1, 1);                                                  \
  WAITV(8); CNS(s0); ISSUE(s0, 2);                                             \
  WAITV(8); CNS(s1); ISSUE(s1, 3);                                             \
  WAITV(8); CNS(s0); ISSUE(s0, 4);                                             \
  WAITV(8); CNS(s1); ISSUE(s1, 5);                                             \
  WAITV(8); CNS(s0); ISSUE(s0, 6);                                             \
  WAITV(8); CNS(s1); ISSUE(s1, 7);                                             \
  WAITV(8); CNS(s0);                                                           \
  WAITV(0); CNS(s1);

__device__ __forceinline__ void zwr(float* b, const f32x4 (&acc)[4][4], int lk, int l15) {
#pragma unroll
  for (int mt = 0; mt < 4; ++mt)
#pragma unroll
    for (int ct = 0; ct < 4; ++ct)
#pragma unroll
      for (int q = 0; q < 4; ++q)
        b[(mt * 16 + lk * 4 + q) * ZP + ct * 16 + l15] = acc[mt][ct][q];
}
__device__ __forceinline__ void zrm(float* b, const f32x4 (&acc)[4][4], int lk, int l15) {
#pragma unroll
  for (int mt = 0; mt < 4; ++mt)
#pragma unroll
    for (int ct = 0; ct < 4; ++ct)
#pragma unroll
      for (int q = 0; q < 4; ++q)
        b[(mt * 16 + lk * 4 + q) * ZP + ct * 16 + l15] += acc[mt][ct][q];
}

// ---- persistent LSTM -------------------------------------------------------
// 64 WGs x 512 thr. WG c owns u in [c*16, c*16+16) -> 64 cols (4 gates).
// Waves 0-3: zx(t+1) = x_{t+1} @ Wx, K-slice wv*256 (off critical path).
// Waves 4-7: zh(t) = h(t) @ Wh, K-slice (wv-4)*256; h from bf16 ping-pong
//   via sc0 sc1 (MALL-coherent). [R13 bug fixed: h A-address uses ks, the
//   K-offset within U — previous round subtracted 1024 and read garbage.]
// Sync: 1-hop all-to-all. Producer wv0 stores 64 flag replicas (1/lane);
// consumer wv4 polls its own 256B row; wv5-7 via LDS gate.
__launch_bounds__(NTHR, 1)
__global__ void lstm_persist(const __hip_bfloat16* __restrict__ xb,
                             const __hip_bfloat16* __restrict__ pWT,
                             const float* __restrict__ bias,
                             const float* __restrict__ h0,
                             const float* __restrict__ c0,
                             __hip_bfloat16* __restrict__ hb,   // [2][B][U] bf16
                             float* __restrict__ out,
                             unsigned* __restrict__ flagmat) {  // [64 cons][64 prod]
  extern __shared__ __align__(16) float zlds[];
  __shared__ unsigned gatew;

  const int tid = threadIdx.x;
  const int wv = tid >> 6;
  const int lane = tid & 63;
  const int l15 = lane & 15;
  const int lk = lane >> 4;
  const int c = blockIdx.x;

  if (tid == 0) gatew = 0;

  const bool isH = (wv >= 4);
  const int ks = (isH ? (wv - 4) : wv) * 256;  // K-offset within D (x) or U (h)

  // B-frag bases (constant over t)
  unsigned long long baddr[4];
#pragma unroll
  for (int ct = 0; ct < 4; ++ct)
    baddr[ct] = (unsigned long long)(pWT + ((size_t)c * NCOL + ct * 16 + l15) * KTOT +
                                     (isH ? Dd : 0) + ks) +
                (unsigned long long)lk * 16;

  // epilogue ownership: row r, two adjacent u's
  const int r = tid >> 3;
  const int eu = (tid & 7) * 2;
  const int u0 = c * UPW + eu;
  float bi[4][2];
#pragma unroll
  for (int g = 0; g < 4; ++g) {
    bi[g][0] = bias[g * Uu + u0];
    bi[g][1] = bias[g * Uu + u0 + 1];
  }
  float cr0 = c0[(size_t)r * Uu + u0];
  float cr1 = c0[(size_t)r * Uu + u0 + 1];

  // init hb buf 0 = h0 (64 WGs x 512 thr x 2 elems cover all 65536 exactly)
  unsigned* hb32 = (unsigned*)hb;
  {
    const int idx2 = c * NTHR + tid;  // word index 0..32767
    union { __hip_bfloat162 v; unsigned u; } pk;
    pk.v.x = __float2bfloat16(h0[2 * idx2]);
    pk.v.y = __float2bfloat16(h0[2 * idx2 + 1]);
    storeSys(&hb32[idx2], pk.u);
  }
  __syncthreads();  // drains init stores (vmcnt) + gatew visible
  if (wv == 0) storeSys(&flagmat[lane * 64 + c], 1u);  // h(0) ready

  f32x4 s0[8], s1[8];
  f32x4 acc[4][4];

  // ---- prologue: zx(0) into parity-0 bufs
  if (!isH) {
#pragma unroll
    for (int mt = 0; mt < 4; ++mt)
#pragma unroll
      for (int ct = 0; ct < 4; ++ct) acc[mt][ct] = (f32x4){0.f, 0.f, 0.f, 0.f};
    unsigned long long xaddr[4];
#pragma unroll
    for (int mt = 0; mt < 4; ++mt)
      xaddr[mt] = (unsigned long long)(xb + ((size_t)(mt * 16 + l15) * Tt + 0) * Dd + ks) +
                  (unsigned long long)lk * 16;
    LADDER(XI);
    if (wv == 0) zwr(zlds + 0 * BUFF, acc, lk, l15);
    if (wv == 2) zwr(zlds + 1 * BUFF, acc, lk, l15);
  }
  __syncthreads();
  if (wv == 1) zrm(zlds + 0 * BUFF, acc, lk, l15);
  if (wv == 3) zrm(zlds + 1 * BUFF, acc, lk, l15);

  for (int t = 0; t < Tt; ++t) {
    const unsigned want = (unsigned)(t + 1);

    // ---- gate (zh waves only): 1-hop flag row poll + LDS gate
    if (wv == 4) {
      const unsigned* fp = flagmat + c * 64 + lane;
      int gd = 0;
      while (pollSys(fp) < want && ++gd < GUARD) __builtin_amdgcn_s_sleep(2);
      if (lane == 0)
        __hip_atomic_store(&gatew, want, __ATOMIC_RELAXED, __HIP_MEMORY_SCOPE_WORKGROUP);
    } else if (wv > 4) {
      int gd = 0;
      while (__hip_atomic_load(&gatew, __ATOMIC_RELAXED, __HIP_MEMORY_SCOPE_WORKGROUP) < want &&
             ++gd < GUARD)
        __builtin_amdgcn_s_sleep(1);
    }
    __builtin_amdgcn_sched_barrier(0);

#pragma unroll
    for (int mt = 0; mt < 4; ++mt)
#pragma unroll
      for (int ct = 0; ct < 4; ++ct) acc[mt][ct] = (f32x4){0.f, 0.f, 0.f, 0.f};

    const int par2 = (t + 1) & 1;  // zx target parity
    if (!isH) {
      const int xt = (t + 1 < Tt) ? t + 1 : t;
      unsigned long long xaddr[4];
#pragma unroll
      for (int mt = 0; mt < 4; ++mt)
        xaddr[mt] = (unsigned long long)(xb + ((size_t)(mt * 16 + l15) * Tt + xt) * Dd + ks) +
                    (unsigned long long)lk * 16;
      LADDER(XI);
      if (wv == 0) zwr(zlds + (par2 * 2 + 0) * BUFF, acc, lk, l15);
      if (wv == 2) zwr(zlds + (par2 * 2 + 1) * BUFF, acc, lk, l15);
    } else {
      const __hip_bfloat16* hcur = hb + (size_t)(t & 1) * (Bb * Uu);
      unsigned long long haddr[4];
#pragma unroll
      for (int mt = 0; mt < 4; ++mt)
        haddr[mt] = (unsigned long long)(hcur + (size_t)(mt * 16 + l15) * Uu + ks) +
                    (unsigned long long)lk * 16;
      LADDER(HI);
      if (wv == 4) zwr(zlds + 4 * BUFF, acc, lk, l15);
      if (wv == 6) zwr(zlds + 5 * BUFF, acc, lk, l15);
    }

    __syncthreads();  // S1: writers done
    if (wv == 1) zrm(zlds + (par2 * 2 + 0) * BUFF, acc, lk, l15);
    if (wv == 3) zrm(zlds + (par2 * 2 + 1) * BUFF, acc, lk, l15);
    if (wv == 5) zrm(zlds + 4 * BUFF, acc, lk, l15);
    if (wv == 7) zrm(zlds + 5 * BUFF, acc, lk, l15);
    __syncthreads();  // S2: partials final

    // ---- epilogue(t): z = zxA+zxB (parity t) + zhA+zhB + bias
    {
      const float* zxA = zlds + ((t & 1) * 2 + 0) * BUFF;
      const float* zxB = zlds + ((t & 1) * 2 + 1) * BUFF;
      const float* zhA = zlds + 4 * BUFF;
      const float* zhB = zlds + 5 * BUFF;
      float zz[4][2];
#pragma unroll
      for (int g = 0; g < 4; ++g) {
        const int idx = r * ZP + g * 16 + eu;
        f32x2 a = *(const f32x2*)&zxA[idx];
        f32x2 b = *(const f32x2*)&zxB[idx];
        f32x2 d = *(const f32x2*)&zhA[idx];
        f32x2 e = *(const f32x2*)&zhB[idx];
        zz[g][0] = a.x + b.x + d.x + e.x + bi[g][0];
        zz[g][1] = a.y + b.y + d.y + e.y + bi[g][1];
      }
      float hv0, hv1;
      {
        float ig = sigm(zz[0][0]), fg = sigm(zz[1][0]);
        float gg = tanhf(zz[2][0]), og = sigm(zz[3][0]);
        cr0 = fg * cr0 + ig * gg;
        hv0 = og * tanhf(cr0);
      }
      {
        float ig = sigm(zz[0][1]), fg = sigm(zz[1][1]);
        float gg = tanhf(zz[2][1]), og = sigm(zz[3][1]);
        cr1 = fg * cr1 + ig * gg;
        hv1 = og * tanhf(cr1);
      }
      f32x2 o2 = {hv0, hv1};
      __builtin_nontemporal_store(o2, (f32x2*)(out + ((size_t)r * Tt + t) * Uu + u0));
      union { __hip_bfloat162 v; unsigned u; } pk;
      pk.v.x = __float2bfloat16(hv0);
      pk.v.y = __float2bfloat16(hv1);
      storeSys(&hb32[(size_t)(((t + 1) & 1) * (Bb * Uu) + r * Uu + u0) >> 1], pk.u);
    }

    __syncthreads();  // S3: drains all waves' h stores (vmcnt) -> MALL-visible
    if (wv == 0) storeSys(&flagmat[lane * 64 + c], (unsigned)(t + 2));
  }
}

// ---- launch ----------------------------------------------------------------

extern "C" void kernel_launch(void* const* d_in, const int* in_sizes, int n_in,
                              void* d_out, int out_size, void* d_ws, size_t ws_size,
                              hipStream_t stream) {
  const float* x = (const float*)d_in[0];
  const float* h0 = (const float*)d_in[1];
  const float* c0 = (const float*)d_in[2];
  const float* Wx = (const float*)d_in[3];
  const float* Wh = (const float*)d_in[4];
  const float* bias = (const float*)d_in[5];
  float* out = (float*)d_out;

  char* ws = (char*)d_ws;
  size_t off = 0;
  __hip_bfloat16* xb = (__hip_bfloat16*)(ws + off);  off += (size_t)Bb * Tt * Dd * 2;       // 64 MB
  __hip_bfloat16* pWT = (__hip_bfloat16*)(ws + off); off += (size_t)NWG * NCOL * KTOT * 2;  // 16.8 MB
  __hip_bfloat16* hb = (__hip_bfloat16*)(ws + off);  off += (size_t)2 * Bb * Uu * 2;        // 256 KB
  unsigned* flagmat = (unsigned*)(ws + off);         off += (size_t)NWG * NWG * 4;          // 16 KB

  hipFuncSetAttribute((const void*)lstm_persist,
                      hipFuncAttributeMaxDynamicSharedMemorySize, DYN_LDS);

  cast_x_bf16<<<4096, 256, 0, stream>>>(x, xb, Bb * Tt * Dd / 4);
  pack_w<<<dim3(4 * Uu / 32, Dd / 32), dim3(32, 8), 0, stream>>>(Wx, pWT, 0);
  pack_w<<<dim3(4 * Uu / 32, Uu / 32), dim3(32, 8), 0, stream>>>(Wh, pWT, Dd);
  hipMemsetAsync(flagmat, 0, (size_t)NWG * NWG * 4, stream);

  lstm_persist<<<NWG, NTHR, DYN_LDS, stream>>>(xb, pWT, bias, h0, c0, hb, out, flagmat);
}